// Round 3
// baseline (291.088 us; speedup 1.0000x reference)
//
#include <hip/hip_runtime.h>
#include <hip/hip_bf16.h>
#include <cmath>
#include <stdint.h>

#define B_ 8
#define T_ 2048
#define C_ 1024
#define HS_ 64
#define NS 8           // key splits per q-tile
#define LP 72          // attn LDS row stride in shorts
#define KCH 256        // proj K-chunk (cols of X staged per iteration)
#define XLP 264        // proj LDS row stride in shorts (132 dwords = 4 mod 32)

typedef __attribute__((ext_vector_type(8))) short short8;    // 8 bf16 (4 VGPRs) - MFMA A/B frag
typedef __attribute__((ext_vector_type(4))) float floatx4;   // MFMA C/D frag

__device__ inline unsigned short f2bf(float f) {
    union { float f; unsigned u; } v; v.f = f;
    unsigned r = v.u + 0x7FFF + ((v.u >> 16) & 1);   // RNE
    return (unsigned short)(r >> 16);
}
__device__ inline unsigned pk2bf(float a, float b) {   // -> v_cvt_pk_bf16_f32
    union { __hip_bfloat162 h; unsigned u; } v;
    v.h = __float22bfloat162_rn(float2{a, b});
    return v.u;
}
__device__ inline float bf2f(unsigned short u) {
    union { unsigned u; float f; } w; w.u = ((unsigned)u) << 16; return w.f;
}

// ---------------------------------------------------------------------------
// Kernel 1: W [C x HS] fp32  ->  W^T [HS x C] bf16  (3 matrices)
// ---------------------------------------------------------------------------
__global__ __launch_bounds__(256) void prep_wt(const float* __restrict__ Wq,
                                               const float* __restrict__ Wk,
                                               const float* __restrict__ Wv,
                                               unsigned short* __restrict__ wt) {
    int p = blockIdx.x >> 4;
    int chunk = blockIdx.x & 15;
    const float* W = (p == 0) ? Wq : (p == 1) ? Wk : Wv;
    unsigned short* WT = wt + p * (C_ * HS_);
    int base = chunk * 4096;
    for (int i = threadIdx.x; i < 4096; i += 256) {
        int idx = base + i;
        int k = idx >> 6, n = idx & 63;
        WT[n * C_ + k] = f2bf(W[idx]);
    }
}

// ---------------------------------------------------------------------------
// Kernel 2: projections. X [16384x1024] fp32 @ W -> bf16 [16384x64]
// grid = 768 (3 proj x 256 row tiles of 64), block = 256 (4 waves, 16 rows each).
// Staging is wave-contiguous: each wave instruction reads 1KB sequential from
// one X row (DRAM-friendly long bursts). A-frags from LDS; W^T B-frags from
// global (32KB slice per kc, L1/L2-hot, shared across all WGs of same p).
// ---------------------------------------------------------------------------
__global__ __launch_bounds__(256) void proj_kernel(
    const float* __restrict__ qv, const float* __restrict__ kv, const float* __restrict__ vv,
    const unsigned short* __restrict__ wt,
    unsigned short* __restrict__ qb, unsigned short* __restrict__ kb, unsigned short* __restrict__ vb)
{
    __shared__ unsigned short Xl[64 * XLP];   // 33.8 KB -> 4 WGs/CU

    const int bid  = blockIdx.x;
    const int p    = bid >> 8;
    const int tile = bid & 255;
    const float* X = (p == 0) ? qv : (p == 1) ? kv : vv;
    const unsigned short* WT = wt + p * (C_ * HS_);
    unsigned short* Ob = (p == 0) ? qb : (p == 1) ? kb : vb;
    const float oscale = (p == 0) ? 0.125f : 1.0f;

    const int tid = threadIdx.x;
    const int wave = tid >> 6, lane = tid & 63, quad = lane >> 4, l16 = lane & 15;
    const long rowbase = (long)tile * 64;

    floatx4 acc[4] = { {0,0,0,0},{0,0,0,0},{0,0,0,0},{0,0,0,0} };

    const int srow = tid >> 5;           // 0..7 (+ r8*8)
    const int sc8  = (tid & 31) * 8;     // float col offset, 32 lanes cover 256 floats

    for (int kc = 0; kc < C_; kc += KCH) {
        // stage 64 rows x 256 cols fp32 -> bf16 LDS (8 rounds x 32B/thread)
        #pragma unroll
        for (int r8 = 0; r8 < 8; ++r8) {
            int row = r8 * 8 + srow;
            const float* gp = X + (rowbase + row) * C_ + kc + sc8;
            floatx4 f0 = *(const floatx4*)gp;
            floatx4 f1 = *(const floatx4*)(gp + 4);
            union { short8 s; unsigned u[4]; } a;
            a.u[0] = pk2bf(f0[0], f0[1]); a.u[1] = pk2bf(f0[2], f0[3]);
            a.u[2] = pk2bf(f1[0], f1[1]); a.u[3] = pk2bf(f1[2], f1[3]);
            *(short8*)&Xl[row * XLP + sc8] = a.s;
        }
        __syncthreads();

        // compute: 8 k-steps of 32, 4 n-tiles
        #pragma unroll
        for (int kcc = 0; kcc < 8; ++kcc) {
            short8 af = *(short8*)&Xl[(wave * 16 + l16) * XLP + kcc * 32 + quad * 8];
            #pragma unroll
            for (int nt = 0; nt < 4; ++nt) {
                short8 bf = *(const short8*)&WT[(nt * 16 + l16) * C_ + kc + kcc * 32 + quad * 8];
                acc[nt] = __builtin_amdgcn_mfma_f32_16x16x32_bf16(af, bf, acc[nt], 0, 0, 0);
            }
        }
        __syncthreads();
    }

    // C-layout: row = quad*4+r, col = nt*16+l16
    #pragma unroll
    for (int nt = 0; nt < 4; ++nt)
        #pragma unroll
        for (int r = 0; r < 4; ++r) {
            long row = rowbase + wave * 16 + quad * 4 + r;
            Ob[row * HS_ + nt * 16 + l16] = f2bf(acc[nt][r] * oscale);
        }
}

// ---------------------------------------------------------------------------
// Kernel 3a: flash attention partials with key-split.
// grid = 8b x 32qt x NS splits = 2048 WGs, block = 256 (4 waves x 16 q-rows).
// ---------------------------------------------------------------------------
__global__ __launch_bounds__(256) void attn_partial(
    const unsigned short* __restrict__ qb, const unsigned short* __restrict__ kb,
    const unsigned short* __restrict__ vb, const int* __restrict__ mask,
    unsigned short* __restrict__ Opart, float* __restrict__ Mpart, float* __restrict__ Lpart)
{
    const int s  = blockIdx.x & (NS - 1);
    const int bq = blockIdx.x >> 3;          // b*32 + qt
    const int qt = bq & 31;
    const int b  = bq >> 5;
    if (s > qt) return;                       // empty split; combine skips it

    __shared__ unsigned short Klds[64 * LP];      // K chunk [key][feat]
    __shared__ unsigned short Vt[64 * LP];        // V chunk transposed [feat][key]
    __shared__ unsigned short Plds[4][16 * LP];   // per-wave P scratch [qrow][key]

    const int tid = threadIdx.x;
    const int wave = tid >> 6, lane = tid & 63, quad = lane >> 4, l16 = lane & 15;

    // Q fragments (A-operand: m = l16, k = quad*8+j); scale folded in.
    const int qrow = qt * 64 + wave * 16 + l16;
    const unsigned short* qp = qb + ((long)(b * T_ + qrow)) * HS_;
    short8 aq0 = *(const short8*)&qp[0  + quad * 8];
    short8 aq1 = *(const short8*)&qp[32 + quad * 8];

    floatx4 acc_o[4] = { {0,0,0,0},{0,0,0,0},{0,0,0,0},{0,0,0,0} };
    float m_r[4] = { -INFINITY, -INFINITY, -INFINITY, -INFINITY };
    float l_r[4] = { 0.f, 0.f, 0.f, 0.f };

    const int rowg = qt * 64 + wave * 16 + quad * 4;

    const int skey = tid >> 3;
    const int sf8  = (tid & 7) * 8;
    const int vp = tid & 31, vg = tid >> 5;

    for (int c = s; c <= qt; c += NS) {
        const int kc = c * 64;
        #pragma unroll
        for (int it = 0; it < 2; ++it) {
            int key = it * 32 + skey;
            *(short8*)&Klds[key * LP + sf8] =
                *(const short8*)&kb[((long)(b * T_ + kc + key)) * HS_ + sf8];
        }
        {
            const unsigned short* v0p = &vb[((long)(b * T_ + kc + 2 * vp)) * HS_ + vg * 8];
            short8 v0 = *(const short8*)v0p;
            short8 v1 = *(const short8*)(v0p + HS_);
            #pragma unroll
            for (int j = 0; j < 8; ++j) {
                unsigned pr = (unsigned)(unsigned short)v0[j] |
                              ((unsigned)(unsigned short)v1[j] << 16);
                *(unsigned*)&Vt[(vg * 8 + j) * LP + 2 * vp] = pr;
            }
        }
        __syncthreads();

        floatx4 sv[4];
        #pragma unroll
        for (int kt = 0; kt < 4; ++kt) {
            floatx4 a = {0.f, 0.f, 0.f, 0.f};
            short8 bk0 = *(short8*)&Klds[(kt * 16 + l16) * LP + 0  + quad * 8];
            short8 bk1 = *(short8*)&Klds[(kt * 16 + l16) * LP + 32 + quad * 8];
            a = __builtin_amdgcn_mfma_f32_16x16x32_bf16(aq0, bk0, a, 0, 0, 0);
            a = __builtin_amdgcn_mfma_f32_16x16x32_bf16(aq1, bk1, a, 0, 0, 0);
            sv[kt] = a;
        }

        const bool lastc = (c == qt);
        #pragma unroll
        for (int kt = 0; kt < 4; ++kt) {
            int key = kc + kt * 16 + l16;
            int mk = mask[b * T_ + key];
            #pragma unroll
            for (int r = 0; r < 4; ++r) {
                bool dead = (mk == 0) || (lastc && key > rowg + r);
                if (dead) sv[kt][r] = -INFINITY;
            }
        }

        float alpha[4];
        #pragma unroll
        for (int r = 0; r < 4; ++r) {
            float mx = fmaxf(fmaxf(sv[0][r], sv[1][r]), fmaxf(sv[2][r], sv[3][r]));
            #pragma unroll
            for (int off = 1; off < 16; off <<= 1)
                mx = fmaxf(mx, __shfl_xor(mx, off));
            float mn = fmaxf(m_r[r], mx);
            float a_ = __expf(m_r[r] - mn);
            float ps = 0.f;
            #pragma unroll
            for (int kt = 0; kt < 4; ++kt) {
                float pv = __expf(sv[kt][r] - mn);
                sv[kt][r] = pv;
                ps += pv;
            }
            #pragma unroll
            for (int off = 1; off < 16; off <<= 1)
                ps += __shfl_xor(ps, off);
            l_r[r] = l_r[r] * a_ + ps;
            m_r[r] = mn;
            alpha[r] = a_;
        }
        #pragma unroll
        for (int nt = 0; nt < 4; ++nt)
            #pragma unroll
            for (int r = 0; r < 4; ++r)
                acc_o[nt][r] *= alpha[r];

        unsigned short* pl = Plds[wave];
        #pragma unroll
        for (int kt = 0; kt < 4; ++kt)
            #pragma unroll
            for (int r = 0; r < 4; ++r)
                pl[(quad * 4 + r) * LP + kt * 16 + l16] = f2bf(sv[kt][r]);
        short8 ap0 = *(short8*)&pl[l16 * LP + 0  + quad * 8];
        short8 ap1 = *(short8*)&pl[l16 * LP + 32 + quad * 8];

        #pragma unroll
        for (int nt = 0; nt < 4; ++nt) {
            short8 bv0 = *(short8*)&Vt[(nt * 16 + l16) * LP + 0  + quad * 8];
            short8 bv1 = *(short8*)&Vt[(nt * 16 + l16) * LP + 32 + quad * 8];
            acc_o[nt] = __builtin_amdgcn_mfma_f32_16x16x32_bf16(ap0, bv0, acc_o[nt], 0, 0, 0);
            acc_o[nt] = __builtin_amdgcn_mfma_f32_16x16x32_bf16(ap1, bv1, acc_o[nt], 0, 0, 0);
        }
        __syncthreads();
    }

    // write partials: O unnormalized (bf16), m/l fp32
    unsigned short* Op = Opart + (long)blockIdx.x * 4096;
    #pragma unroll
    for (int nt = 0; nt < 4; ++nt)
        #pragma unroll
        for (int r = 0; r < 4; ++r)
            Op[(wave * 16 + quad * 4 + r) * 64 + nt * 16 + l16] = f2bf(acc_o[nt][r]);
    if (l16 == 0) {
        #pragma unroll
        for (int r = 0; r < 4; ++r) {
            int rl = wave * 16 + quad * 4 + r;
            Mpart[(long)blockIdx.x * 64 + rl] = m_r[r];
            Lpart[(long)blockIdx.x * 64 + rl] = l_r[r];
        }
    }
}

// ---------------------------------------------------------------------------
// Kernel 3b: combine split partials. grid = 8b x 32qt x 2 = 512, block = 256.
// ---------------------------------------------------------------------------
__global__ __launch_bounds__(256) void attn_combine(
    const unsigned short* __restrict__ Opart, const float* __restrict__ Mpart,
    const float* __restrict__ Lpart, float* __restrict__ out)
{
    const int half = blockIdx.x & 1;
    const int bq = blockIdx.x >> 1;
    const int qt = bq & 31;
    const int b  = bq >> 5;
    const int nsp = (qt + 1 < NS) ? qt + 1 : NS;

    const int row  = (threadIdx.x >> 3) + half * 32;   // 0..63
    const int colg = (threadIdx.x & 7) * 8;
    const long base = (long)bq * NS;

    float M = -INFINITY;
    #pragma unroll
    for (int sp = 0; sp < NS; ++sp)
        if (sp < nsp) M = fmaxf(M, Mpart[(base + sp) * 64 + row]);

    float w[NS];
    float L = 0.f;
    #pragma unroll
    for (int sp = 0; sp < NS; ++sp)
        if (sp < nsp) {
            float e = __expf(Mpart[(base + sp) * 64 + row] - M);
            w[sp] = e;
            L += e * Lpart[(base + sp) * 64 + row];
        }

    float acc[8] = {0,0,0,0,0,0,0,0};
    #pragma unroll
    for (int sp = 0; sp < NS; ++sp)
        if (sp < nsp) {
            const unsigned short* Op = Opart + (base + sp) * 4096 + row * 64 + colg;
            short8 o = *(const short8*)Op;
            float ws = w[sp];
            #pragma unroll
            for (int j = 0; j < 8; ++j)
                acc[j] += ws * bf2f((unsigned short)o[j]);
        }

    float inv = 1.0f / L;
    float* op = out + ((long)(b * T_ + qt * 64 + row)) * HS_ + colg;
    floatx4 o0 = { acc[0] * inv, acc[1] * inv, acc[2] * inv, acc[3] * inv };
    floatx4 o1 = { acc[4] * inv, acc[5] * inv, acc[6] * inv, acc[7] * inv };
    *(floatx4*)op = o0;
    *(floatx4*)(op + 4) = o1;
}

// ---------------------------------------------------------------------------
extern "C" void kernel_launch(void* const* d_in, const int* in_sizes, int n_in,
                              void* d_out, int out_size, void* d_ws, size_t ws_size,
                              hipStream_t stream)
{
    const float* qv = (const float*)d_in[0];
    const float* kv = (const float*)d_in[1];
    const float* vv = (const float*)d_in[2];
    const int*   mask = (const int*)d_in[3];
    const float* Wq = (const float*)d_in[4];
    const float* Wk = (const float*)d_in[5];
    const float* Wv = (const float*)d_in[6];
    float* out = (float*)d_out;

    // ws layout: W^T x3 | q/k/v bf16 | O partials bf16 | M,L fp32  (~24.2 MB)
    unsigned short* wt    = (unsigned short*)d_ws;
    unsigned short* qbuf  = wt + 3 * C_ * HS_;
    unsigned short* kbuf  = qbuf + (long)B_ * T_ * HS_;
    unsigned short* vbuf  = kbuf + (long)B_ * T_ * HS_;
    unsigned short* Opart = vbuf + (long)B_ * T_ * HS_;
    float* Mpart = (float*)(Opart + (long)B_ * 32 * NS * 4096);
    float* Lpart = Mpart + (long)B_ * 32 * NS * 64;

    prep_wt<<<48, 256, 0, stream>>>(Wq, Wk, Wv, wt);
    proj_kernel<<<768, 256, 0, stream>>>(qv, kv, vv, wt, qbuf, kbuf, vbuf);
    attn_partial<<<B_ * 32 * NS, 256, 0, stream>>>(qbuf, kbuf, vbuf, mask, Opart, Mpart, Lpart);
    attn_combine<<<B_ * 32 * 2, 256, 0, stream>>>(Opart, Mpart, Lpart, out);
}

// Round 4
// 260.352 us; speedup vs baseline: 1.1181x; 1.1181x over previous
//
#include <hip/hip_runtime.h>
#include <hip/hip_bf16.h>
#include <cmath>
#include <stdint.h>

#define B_ 8
#define T_ 2048
#define C_ 1024
#define HS_ 64
#define NS 8           // key splits per q-tile
#define LP 72          // attn LDS row stride in shorts
#define PKC 128        // proj K-chunk width (elements)
#define XLP2 136       // proj LDS row stride in shorts (272B rows: 16B aligned, 4-bank phase step)

typedef __attribute__((ext_vector_type(8))) short short8;    // 8 bf16 (4 VGPRs) - MFMA A/B frag
typedef __attribute__((ext_vector_type(4))) float floatx4;   // MFMA C/D frag

__device__ inline unsigned short f2bf(float f) {
    union { float f; unsigned u; } v; v.f = f;
    unsigned r = v.u + 0x7FFF + ((v.u >> 16) & 1);   // RNE
    return (unsigned short)(r >> 16);
}
__device__ inline unsigned pk2bf(float a, float b) {   // -> v_cvt_pk_bf16_f32
    union { __hip_bfloat162 h; unsigned u; } v;
    v.h = __float22bfloat162_rn(float2{a, b});
    return v.u;
}
__device__ inline float bf2f(unsigned short u) {
    union { unsigned u; float f; } w; w.u = ((unsigned)u) << 16; return w.f;
}

// ---------------------------------------------------------------------------
// Kernel 1: W [C x HS] fp32  ->  W^T [HS x C] bf16  (3 matrices)
// ---------------------------------------------------------------------------
__global__ __launch_bounds__(256) void prep_wt(const float* __restrict__ Wq,
                                               const float* __restrict__ Wk,
                                               const float* __restrict__ Wv,
                                               unsigned short* __restrict__ wt) {
    int p = blockIdx.x >> 4;
    int chunk = blockIdx.x & 15;
    const float* W = (p == 0) ? Wq : (p == 1) ? Wk : Wv;
    unsigned short* WT = wt + p * (C_ * HS_);
    int base = chunk * 4096;
    for (int i = threadIdx.x; i < 4096; i += 256) {
        int idx = base + i;
        int k = idx >> 6, n = idx & 63;
        WT[n * C_ + k] = f2bf(W[idx]);
    }
}

// ---------------------------------------------------------------------------
// Kernel 2: projections. X [16384x1024] fp32 @ W [1024x64] -> bf16 [16384x64]
// grid = 768 (3 proj x 256 row tiles of 64), block = 256 (4 waves).
// Software-pipelined: inner loop is pure LDS+MFMA; next chunk's X and W^T are
// prefetched into REGISTERS right after the barrier so global loads fly
// during compute. No inner-loop global gathers (round-3 bottleneck).
// ---------------------------------------------------------------------------
__global__ __launch_bounds__(256, 4) void proj_kernel(
    const float* __restrict__ qv, const float* __restrict__ kv, const float* __restrict__ vv,
    const unsigned short* __restrict__ wt,
    unsigned short* __restrict__ qb, unsigned short* __restrict__ kb, unsigned short* __restrict__ vb)
{
    __shared__ unsigned short Xl[64 * XLP2];   // 17.4 KB
    __shared__ unsigned short Wl[64 * XLP2];   // 17.4 KB  -> 4 WGs/CU

    const int bid  = blockIdx.x;
    const int p    = bid >> 8;
    const int tile = bid & 255;
    const float* X = (p == 0) ? qv : (p == 1) ? kv : vv;
    const unsigned short* WT = wt + p * (C_ * HS_);
    unsigned short* Ob = (p == 0) ? qb : (p == 1) ? kb : vb;
    const float oscale = (p == 0) ? 0.125f : 1.0f;

    const int tid = threadIdx.x;
    const int wave = tid >> 6, lane = tid & 63, quad = lane >> 4, l16 = lane & 15;
    const long rowbase = (long)tile * 64;
    const float* Xbase = X + rowbase * C_;

    // X staging: instr i (0..7): row = wave*16 + i*2 + xrp, cols xsub*4..+3 (fp32)
    const int xsub = lane & 31;
    const int xrp  = lane >> 5;
    // W staging: instr i (0..3): row = wave*16 + i*4 + wr4, cols wsub*8..+7 (bf16)
    const int wsub = lane & 15;
    const int wr4  = lane >> 4;

    floatx4 xf[8];
    short8  wf[4];

    // prologue: chunk 0 into regs
    #pragma unroll
    for (int i = 0; i < 8; ++i)
        xf[i] = *(const floatx4*)(Xbase + (wave * 16 + i * 2 + xrp) * C_ + xsub * 4);
    #pragma unroll
    for (int i = 0; i < 4; ++i)
        wf[i] = *(const short8*)(WT + (wave * 16 + i * 4 + wr4) * C_ + wsub * 8);

    floatx4 acc[4] = { {0,0,0,0},{0,0,0,0},{0,0,0,0},{0,0,0,0} };

    for (int c = 0; c < C_ / PKC; ++c) {
        // drain staged regs to LDS (X: cvt fp32->bf16)
        #pragma unroll
        for (int i = 0; i < 8; ++i) {
            int row = wave * 16 + i * 2 + xrp;
            unsigned u0 = pk2bf(xf[i][0], xf[i][1]);
            unsigned u1 = pk2bf(xf[i][2], xf[i][3]);
            unsigned* d = (unsigned*)&Xl[row * XLP2 + xsub * 4];
            d[0] = u0; d[1] = u1;
        }
        #pragma unroll
        for (int i = 0; i < 4; ++i)
            *(short8*)&Wl[(wave * 16 + i * 4 + wr4) * XLP2 + wsub * 8] = wf[i];
        __syncthreads();

        // prefetch next chunk into regs (flies during the MFMA block below)
        if (c + 1 < C_ / PKC) {
            const int kc = (c + 1) * PKC;
            #pragma unroll
            for (int i = 0; i < 8; ++i)
                xf[i] = *(const floatx4*)(Xbase + (wave * 16 + i * 2 + xrp) * C_ + kc + xsub * 4);
            #pragma unroll
            for (int i = 0; i < 4; ++i)
                wf[i] = *(const short8*)(WT + (wave * 16 + i * 4 + wr4) * C_ + kc + wsub * 8);
        }

        // compute: pure LDS + MFMA (4 k-steps x 4 n-tiles)
        #pragma unroll
        for (int kcc = 0; kcc < 4; ++kcc) {
            short8 af = *(short8*)&Xl[(wave * 16 + l16) * XLP2 + kcc * 32 + quad * 8];
            #pragma unroll
            for (int nt = 0; nt < 4; ++nt) {
                short8 bf = *(short8*)&Wl[(nt * 16 + l16) * XLP2 + kcc * 32 + quad * 8];
                acc[nt] = __builtin_amdgcn_mfma_f32_16x16x32_bf16(af, bf, acc[nt], 0, 0, 0);
            }
        }
        __syncthreads();
    }

    // C-layout: row = quad*4+r (X row), col = nt*16+l16 (h)
    #pragma unroll
    for (int nt = 0; nt < 4; ++nt)
        #pragma unroll
        for (int r = 0; r < 4; ++r) {
            long row = rowbase + wave * 16 + quad * 4 + r;
            Ob[row * HS_ + nt * 16 + l16] = f2bf(acc[nt][r] * oscale);
        }
}

// ---------------------------------------------------------------------------
// Kernel 3a: flash attention partials with key-split.
// grid = 8b x 32qt x NS splits = 2048 WGs, block = 256 (4 waves x 16 q-rows).
// ---------------------------------------------------------------------------
__global__ __launch_bounds__(256) void attn_partial(
    const unsigned short* __restrict__ qb, const unsigned short* __restrict__ kb,
    const unsigned short* __restrict__ vb, const int* __restrict__ mask,
    unsigned short* __restrict__ Opart, float* __restrict__ Mpart, float* __restrict__ Lpart)
{
    const int s  = blockIdx.x & (NS - 1);
    const int bq = blockIdx.x >> 3;          // b*32 + qt
    const int qt = bq & 31;
    const int b  = bq >> 5;
    if (s > qt) return;                       // empty split; combine skips it

    __shared__ unsigned short Klds[64 * LP];      // K chunk [key][feat]
    __shared__ unsigned short Vt[64 * LP];        // V chunk transposed [feat][key]
    __shared__ unsigned short Plds[4][16 * LP];   // per-wave P scratch [qrow][key]

    const int tid = threadIdx.x;
    const int wave = tid >> 6, lane = tid & 63, quad = lane >> 4, l16 = lane & 15;

    // Q fragments (A-operand: m = l16, k = quad*8+j); scale folded in.
    const int qrow = qt * 64 + wave * 16 + l16;
    const unsigned short* qp = qb + ((long)(b * T_ + qrow)) * HS_;
    short8 aq0 = *(const short8*)&qp[0  + quad * 8];
    short8 aq1 = *(const short8*)&qp[32 + quad * 8];

    floatx4 acc_o[4] = { {0,0,0,0},{0,0,0,0},{0,0,0,0},{0,0,0,0} };
    float m_r[4] = { -INFINITY, -INFINITY, -INFINITY, -INFINITY };
    float l_r[4] = { 0.f, 0.f, 0.f, 0.f };

    const int rowg = qt * 64 + wave * 16 + quad * 4;

    const int skey = tid >> 3;
    const int sf8  = (tid & 7) * 8;
    const int vp = tid & 31, vg = tid >> 5;

    for (int c = s; c <= qt; c += NS) {
        const int kc = c * 64;
        #pragma unroll
        for (int it = 0; it < 2; ++it) {
            int key = it * 32 + skey;
            *(short8*)&Klds[key * LP + sf8] =
                *(const short8*)&kb[((long)(b * T_ + kc + key)) * HS_ + sf8];
        }
        {
            const unsigned short* v0p = &vb[((long)(b * T_ + kc + 2 * vp)) * HS_ + vg * 8];
            short8 v0 = *(const short8*)v0p;
            short8 v1 = *(const short8*)(v0p + HS_);
            #pragma unroll
            for (int j = 0; j < 8; ++j) {
                unsigned pr = (unsigned)(unsigned short)v0[j] |
                              ((unsigned)(unsigned short)v1[j] << 16);
                *(unsigned*)&Vt[(vg * 8 + j) * LP + 2 * vp] = pr;
            }
        }
        __syncthreads();

        floatx4 sv[4];
        #pragma unroll
        for (int kt = 0; kt < 4; ++kt) {
            floatx4 a = {0.f, 0.f, 0.f, 0.f};
            short8 bk0 = *(short8*)&Klds[(kt * 16 + l16) * LP + 0  + quad * 8];
            short8 bk1 = *(short8*)&Klds[(kt * 16 + l16) * LP + 32 + quad * 8];
            a = __builtin_amdgcn_mfma_f32_16x16x32_bf16(aq0, bk0, a, 0, 0, 0);
            a = __builtin_amdgcn_mfma_f32_16x16x32_bf16(aq1, bk1, a, 0, 0, 0);
            sv[kt] = a;
        }

        const bool lastc = (c == qt);
        #pragma unroll
        for (int kt = 0; kt < 4; ++kt) {
            int key = kc + kt * 16 + l16;
            int mk = mask[b * T_ + key];
            #pragma unroll
            for (int r = 0; r < 4; ++r) {
                bool dead = (mk == 0) || (lastc && key > rowg + r);
                if (dead) sv[kt][r] = -INFINITY;
            }
        }

        float alpha[4];
        #pragma unroll
        for (int r = 0; r < 4; ++r) {
            float mx = fmaxf(fmaxf(sv[0][r], sv[1][r]), fmaxf(sv[2][r], sv[3][r]));
            #pragma unroll
            for (int off = 1; off < 16; off <<= 1)
                mx = fmaxf(mx, __shfl_xor(mx, off));
            float mn = fmaxf(m_r[r], mx);
            float a_ = __expf(m_r[r] - mn);
            float ps = 0.f;
            #pragma unroll
            for (int kt = 0; kt < 4; ++kt) {
                float pv = __expf(sv[kt][r] - mn);
                sv[kt][r] = pv;
                ps += pv;
            }
            #pragma unroll
            for (int off = 1; off < 16; off <<= 1)
                ps += __shfl_xor(ps, off);
            l_r[r] = l_r[r] * a_ + ps;
            m_r[r] = mn;
            alpha[r] = a_;
        }
        #pragma unroll
        for (int nt = 0; nt < 4; ++nt)
            #pragma unroll
            for (int r = 0; r < 4; ++r)
                acc_o[nt][r] *= alpha[r];

        unsigned short* pl = Plds[wave];
        #pragma unroll
        for (int kt = 0; kt < 4; ++kt)
            #pragma unroll
            for (int r = 0; r < 4; ++r)
                pl[(quad * 4 + r) * LP + kt * 16 + l16] = f2bf(sv[kt][r]);
        short8 ap0 = *(short8*)&pl[l16 * LP + 0  + quad * 8];
        short8 ap1 = *(short8*)&pl[l16 * LP + 32 + quad * 8];

        #pragma unroll
        for (int nt = 0; nt < 4; ++nt) {
            short8 bv0 = *(short8*)&Vt[(nt * 16 + l16) * LP + 0  + quad * 8];
            short8 bv1 = *(short8*)&Vt[(nt * 16 + l16) * LP + 32 + quad * 8];
            acc_o[nt] = __builtin_amdgcn_mfma_f32_16x16x32_bf16(ap0, bv0, acc_o[nt], 0, 0, 0);
            acc_o[nt] = __builtin_amdgcn_mfma_f32_16x16x32_bf16(ap1, bv1, acc_o[nt], 0, 0, 0);
        }
        __syncthreads();
    }

    // write partials: O unnormalized (bf16), m/l fp32
    unsigned short* Op = Opart + (long)blockIdx.x * 4096;
    #pragma unroll
    for (int nt = 0; nt < 4; ++nt)
        #pragma unroll
        for (int r = 0; r < 4; ++r)
            Op[(wave * 16 + quad * 4 + r) * 64 + nt * 16 + l16] = f2bf(acc_o[nt][r]);
    if (l16 == 0) {
        #pragma unroll
        for (int r = 0; r < 4; ++r) {
            int rl = wave * 16 + quad * 4 + r;
            Mpart[(long)blockIdx.x * 64 + rl] = m_r[r];
            Lpart[(long)blockIdx.x * 64 + rl] = l_r[r];
        }
    }
}

// ---------------------------------------------------------------------------
// Kernel 3b: combine split partials. grid = 8b x 32qt x 2 = 512, block = 256.
// ---------------------------------------------------------------------------
__global__ __launch_bounds__(256) void attn_combine(
    const unsigned short* __restrict__ Opart, const float* __restrict__ Mpart,
    const float* __restrict__ Lpart, float* __restrict__ out)
{
    const int half = blockIdx.x & 1;
    const int bq = blockIdx.x >> 1;
    const int qt = bq & 31;
    const int b  = bq >> 5;
    const int nsp = (qt + 1 < NS) ? qt + 1 : NS;

    const int row  = (threadIdx.x >> 3) + half * 32;   // 0..63
    const int colg = (threadIdx.x & 7) * 8;
    const long base = (long)bq * NS;

    float M = -INFINITY;
    #pragma unroll
    for (int sp = 0; sp < NS; ++sp)
        if (sp < nsp) M = fmaxf(M, Mpart[(base + sp) * 64 + row]);

    float w[NS];
    float L = 0.f;
    #pragma unroll
    for (int sp = 0; sp < NS; ++sp)
        if (sp < nsp) {
            float e = __expf(Mpart[(base + sp) * 64 + row] - M);
            w[sp] = e;
            L += e * Lpart[(base + sp) * 64 + row];
        }

    float acc[8] = {0,0,0,0,0,0,0,0};
    #pragma unroll
    for (int sp = 0; sp < NS; ++sp)
        if (sp < nsp) {
            const unsigned short* Op = Opart + (base + sp) * 4096 + row * 64 + colg;
            short8 o = *(const short8*)Op;
            float ws = w[sp];
            #pragma unroll
            for (int j = 0; j < 8; ++j)
                acc[j] += ws * bf2f((unsigned short)o[j]);
        }

    float inv = 1.0f / L;
    float* op = out + ((long)(b * T_ + qt * 64 + row)) * HS_ + colg;
    floatx4 o0 = { acc[0] * inv, acc[1] * inv, acc[2] * inv, acc[3] * inv };
    floatx4 o1 = { acc[4] * inv, acc[5] * inv, acc[6] * inv, acc[7] * inv };
    *(floatx4*)op = o0;
    *(floatx4*)(op + 4) = o1;
}

// ---------------------------------------------------------------------------
extern "C" void kernel_launch(void* const* d_in, const int* in_sizes, int n_in,
                              void* d_out, int out_size, void* d_ws, size_t ws_size,
                              hipStream_t stream)
{
    const float* qv = (const float*)d_in[0];
    const float* kv = (const float*)d_in[1];
    const float* vv = (const float*)d_in[2];
    const int*   mask = (const int*)d_in[3];
    const float* Wq = (const float*)d_in[4];
    const float* Wk = (const float*)d_in[5];
    const float* Wv = (const float*)d_in[6];
    float* out = (float*)d_out;

    // ws layout: W^T x3 | q/k/v bf16 | O partials bf16 | M,L fp32  (~24.2 MB)
    unsigned short* wt    = (unsigned short*)d_ws;
    unsigned short* qbuf  = wt + 3 * C_ * HS_;
    unsigned short* kbuf  = qbuf + (long)B_ * T_ * HS_;
    unsigned short* vbuf  = kbuf + (long)B_ * T_ * HS_;
    unsigned short* Opart = vbuf + (long)B_ * T_ * HS_;
    float* Mpart = (float*)(Opart + (long)B_ * 32 * NS * 4096);
    float* Lpart = Mpart + (long)B_ * 32 * NS * 64;

    prep_wt<<<48, 256, 0, stream>>>(Wq, Wk, Wv, wt);
    proj_kernel<<<768, 256, 0, stream>>>(qv, kv, vv, wt, qbuf, kbuf, vbuf);
    attn_partial<<<B_ * 32 * NS, 256, 0, stream>>>(qbuf, kbuf, vbuf, mask, Opart, Mpart, Lpart);
    attn_combine<<<B_ * 32 * 2, 256, 0, stream>>>(Opart, Mpart, Lpart, out);
}